// Round 1
// baseline (5347.194 us; speedup 1.0000x reference)
//
#include <hip/hip_runtime.h>
#include <math.h>

#define B_    4096
#define CIN   60
#define CW    32
#define EMB   512
#define TSTEP 50
#define KFC   1152   // CW*6*6
#define G3    1536   // 3*EMB

// ---------------- conv 3x3 VALID + relu, one block per batch image ----------------
__global__ __launch_bounds__(288) void conv_relu_kernel(
    const float* __restrict__ x, const float* __restrict__ w,
    const float* __restrict__ bias, float* __restrict__ out)
{
    __shared__ float xs[CIN * 64];
    int b = blockIdx.x;
    const float* xb = x + (size_t)b * (CIN * 64);
    for (int i = threadIdx.x; i < CIN * 16; i += 288)
        ((float4*)xs)[i] = ((const float4*)xb)[i];
    __syncthreads();

    for (int o = threadIdx.x; o < CW * 36; o += 288) {
        int co = o / 36, pos = o % 36;
        int oh = pos / 6, ow = pos % 6;
        const float* wc = w + co * (CIN * 9);
        const float* xp = xs + oh * 8 + ow;
        float s = bias[co];
        #pragma unroll 4
        for (int ci = 0; ci < CIN; ci++) {
            const float* xr = xp + ci * 64;
            const float* wr = wc + ci * 9;
            s += xr[0]  * wr[0] + xr[1]  * wr[1] + xr[2]  * wr[2]
               + xr[8]  * wr[3] + xr[9]  * wr[4] + xr[10] * wr[5]
               + xr[16] * wr[6] + xr[17] * wr[7] + xr[18] * wr[8];
        }
        out[(size_t)b * KFC + o] = fmaxf(s, 0.f);
    }
}

// ---------------- C = A(MxK) * B(NxK)^T + bias, optional relu ----------------
// 64x64 tile, BK=16, 256 threads, 4x4 micro-tile per thread.
template<bool RELU>
__global__ __launch_bounds__(256) void gemm_bt(
    const float* __restrict__ A, const float* __restrict__ Bm,
    const float* __restrict__ bias, float* __restrict__ C,
    int M, int N, int K)
{
    __shared__ __align__(16) float As[16][68];
    __shared__ __align__(16) float Bs[16][68];
    int m0 = blockIdx.y * 64, n0 = blockIdx.x * 64;
    int tid = threadIdx.x;
    int lr = tid >> 2;       // 0..63
    int lc = tid & 3;        // 0..3  (float4 along K)
    int ty = tid >> 4;       // 0..15
    int tx = tid & 15;       // 0..15
    float acc[4][4] = {};

    for (int k0 = 0; k0 < K; k0 += 16) {
        float4 av = *(const float4*)(A  + (size_t)(m0 + lr) * K + k0 + lc * 4);
        float4 bv = *(const float4*)(Bm + (size_t)(n0 + lr) * K + k0 + lc * 4);
        As[lc * 4 + 0][lr] = av.x; As[lc * 4 + 1][lr] = av.y;
        As[lc * 4 + 2][lr] = av.z; As[lc * 4 + 3][lr] = av.w;
        Bs[lc * 4 + 0][lr] = bv.x; Bs[lc * 4 + 1][lr] = bv.y;
        Bs[lc * 4 + 2][lr] = bv.z; Bs[lc * 4 + 3][lr] = bv.w;
        __syncthreads();
        #pragma unroll
        for (int kk = 0; kk < 16; kk++) {
            float4 a = *(const float4*)&As[kk][ty * 4];
            float4 b = *(const float4*)&Bs[kk][tx * 4];
            float ar[4] = {a.x, a.y, a.z, a.w};
            float br[4] = {b.x, b.y, b.z, b.w};
            #pragma unroll
            for (int i = 0; i < 4; i++)
                #pragma unroll
                for (int j = 0; j < 4; j++)
                    acc[i][j] = fmaf(ar[i], br[j], acc[i][j]);
        }
        __syncthreads();
    }

    #pragma unroll
    for (int i = 0; i < 4; i++) {
        int m = m0 + ty * 4 + i;
        #pragma unroll
        for (int j = 0; j < 4; j++) {
            int n = n0 + tx * 4 + j;
            float v = acc[i][j] + bias[n];
            if (RELU) v = fmaxf(v, 0.f);
            C[(size_t)m * N + n] = v;
        }
    }
}

// ---------------- fused GRU gates + h update + decoder dot ----------------
__global__ __launch_bounds__(512) void gru_gate(
    const float* __restrict__ gh, float* __restrict__ h,
    const float* __restrict__ w_ih, const float* __restrict__ b_ih,
    const float* __restrict__ dec_w, const float* __restrict__ dec_b,
    float* __restrict__ prev_out, float* __restrict__ out, int t)
{
    __shared__ float red[8];
    int b = blockIdx.x, e = threadIdx.x;
    float prev = (t == 0) ? 0.f : prev_out[b];
    const float* ghb = gh + (size_t)b * G3;

    float gr = fmaf(prev, w_ih[e],           b_ih[e])           + ghb[e];
    float gz = fmaf(prev, w_ih[EMB + e],     b_ih[EMB + e])     + ghb[EMB + e];
    float gn = fmaf(prev, w_ih[2 * EMB + e], b_ih[2 * EMB + e]);
    float hp = h[(size_t)b * EMB + e];

    float r = 1.f / (1.f + expf(-gr));
    float z = 1.f / (1.f + expf(-gz));
    float n = tanhf(gn + r * ghb[2 * EMB + e]);
    float hn = (1.f - z) * n + z * hp;
    h[(size_t)b * EMB + e] = hn;

    float v = hn * dec_w[e];
    #pragma unroll
    for (int off = 32; off > 0; off >>= 1) v += __shfl_down(v, off, 64);
    int wv = e >> 6, ln = e & 63;
    if (ln == 0) red[wv] = v;
    __syncthreads();
    if (e == 0) {
        float s = red[0] + red[1] + red[2] + red[3]
                + red[4] + red[5] + red[6] + red[7] + dec_b[0];
        out[(size_t)b * TSTEP + t] = s;
        prev_out[b] = s;
    }
}

extern "C" void kernel_launch(void* const* d_in, const int* in_sizes, int n_in,
                              void* d_out, int out_size, void* d_ws, size_t ws_size,
                              hipStream_t stream)
{
    const float* x      = (const float*)d_in[0];
    const float* conv_w = (const float*)d_in[1];
    const float* conv_b = (const float*)d_in[2];
    const float* fc_w   = (const float*)d_in[3];
    const float* fc_b   = (const float*)d_in[4];
    const float* w_ih   = (const float*)d_in[5];
    const float* b_ih   = (const float*)d_in[6];
    const float* w_hh   = (const float*)d_in[7];
    const float* b_hh   = (const float*)d_in[8];
    const float* dec_w  = (const float*)d_in[9];
    const float* dec_b  = (const float*)d_in[10];
    float* out = (float*)d_out;

    char* ws = (char*)d_ws;
    float* gh   = (float*)ws;                                   // B x 1536 (25.2 MB)
    float* conv = (float*)ws;                                   // alias: B x 1152 (18.9 MB)
    float* h    = (float*)(ws + (size_t)B_ * G3 * 4);           // B x 512 (8 MB)
    float* pout = (float*)(ws + (size_t)B_ * G3 * 4
                              + (size_t)B_ * EMB * 4);          // B (16 KB)

    conv_relu_kernel<<<B_, 288, 0, stream>>>(x, conv_w, conv_b, conv);
    gemm_bt<true><<<dim3(EMB / 64, B_ / 64), 256, 0, stream>>>(
        conv, fc_w, fc_b, h, B_, EMB, KFC);

    for (int t = 0; t < TSTEP; t++) {
        gemm_bt<false><<<dim3(G3 / 64, B_ / 64), 256, 0, stream>>>(
            h, w_hh, b_hh, gh, B_, G3, EMB);
        gru_gate<<<B_, 512, 0, stream>>>(
            gh, h, w_ih, b_ih, dec_w, dec_b, pout, out, t);
    }
}

// Round 2
// 3196.106 us; speedup vs baseline: 1.6730x; 1.6730x over previous
//
#include <hip/hip_runtime.h>
#include <math.h>

#define B_    4096
#define CIN   60
#define CW    32
#define EMB   512
#define TSTEP 50
#define KFC   1152   // CW*6*6
#define G3    1536   // 3*EMB
#define LDSK  72     // 64 + 8 pad, in f16 units (144 B row stride, 16B-aligned)

typedef _Float16 f16;
typedef _Float16 f16x8 __attribute__((ext_vector_type(8)));
typedef float    f32x16 __attribute__((ext_vector_type(16)));

__device__ __forceinline__ float sigmoid_fast(float x) {
    return 1.f / (1.f + __expf(-x));
}
__device__ __forceinline__ float tanh_fast(float x) {
    float e = __expf(2.f * x);
    return 1.f - 2.f / (e + 1.f);
}

// ---------------- conv 3x3 VALID + relu ----------------
// wave-resident image plane: lane = pixel (8x8), window via shfl, weights scalar.
__global__ __launch_bounds__(256) void conv_relu_kernel(
    const float* __restrict__ x, const float* __restrict__ w,
    const float* __restrict__ bias, float* __restrict__ out)
{
    int wid = threadIdx.x >> 6, lane = threadIdx.x & 63;
    int oh = lane >> 3, ow = lane & 7;
    bool valid = (oh < 6) && (ow < 6);
    int pos = oh * 6 + ow;

    for (int i = 0; i < 2; i++) {
        int b = blockIdx.x * 8 + wid * 2 + i;
        const float* xb = x + (size_t)b * (CIN * 64);
        float acc[CW];
        #pragma unroll
        for (int co = 0; co < CW; co++) acc[co] = bias[co];

        #pragma unroll 1
        for (int ci = 0; ci < CIN; ci++) {
            float xv = xb[ci * 64 + lane];          // coalesced 256B/wave
            float n0 = __shfl(xv, lane + 0,  64);
            float n1 = __shfl(xv, lane + 1,  64);
            float n2 = __shfl(xv, lane + 2,  64);
            float n3 = __shfl(xv, lane + 8,  64);
            float n4 = __shfl(xv, lane + 9,  64);
            float n5 = __shfl(xv, lane + 10, 64);
            float n6 = __shfl(xv, lane + 16, 64);
            float n7 = __shfl(xv, lane + 17, 64);
            float n8 = __shfl(xv, lane + 18, 64);
            #pragma unroll
            for (int co = 0; co < CW; co++) {
                const float* wp = w + (co * CIN + ci) * 9;   // wave-uniform -> s_load
                float s = acc[co];
                s = fmaf(n0, wp[0], s); s = fmaf(n1, wp[1], s); s = fmaf(n2, wp[2], s);
                s = fmaf(n3, wp[3], s); s = fmaf(n4, wp[4], s); s = fmaf(n5, wp[5], s);
                s = fmaf(n6, wp[6], s); s = fmaf(n7, wp[7], s); s = fmaf(n8, wp[8], s);
                acc[co] = s;
            }
        }
        if (valid) {
            float* ob = out + (size_t)b * KFC;
            #pragma unroll
            for (int co = 0; co < CW; co++)
                ob[co * 36 + pos] = fmaxf(acc[co], 0.f);
        }
    }
}

// ---------------- fp32 GEMM C = A(MxK) * B(NxK)^T + bias, relu, + f16 copy ----------------
__global__ __launch_bounds__(256) void gemm_bt_relu16(
    const float* __restrict__ A, const float* __restrict__ Bm,
    const float* __restrict__ bias, float* __restrict__ C,
    f16* __restrict__ C16, int M, int N, int K)
{
    __shared__ __align__(16) float As[16][68];
    __shared__ __align__(16) float Bs[16][68];
    int m0 = blockIdx.y * 64, n0 = blockIdx.x * 64;
    int tid = threadIdx.x;
    int lr = tid >> 2, lc = tid & 3;
    int ty = tid >> 4, tx = tid & 15;
    float acc[4][4] = {};

    for (int k0 = 0; k0 < K; k0 += 16) {
        float4 av = *(const float4*)(A  + (size_t)(m0 + lr) * K + k0 + lc * 4);
        float4 bv = *(const float4*)(Bm + (size_t)(n0 + lr) * K + k0 + lc * 4);
        As[lc * 4 + 0][lr] = av.x; As[lc * 4 + 1][lr] = av.y;
        As[lc * 4 + 2][lr] = av.z; As[lc * 4 + 3][lr] = av.w;
        Bs[lc * 4 + 0][lr] = bv.x; Bs[lc * 4 + 1][lr] = bv.y;
        Bs[lc * 4 + 2][lr] = bv.z; Bs[lc * 4 + 3][lr] = bv.w;
        __syncthreads();
        #pragma unroll
        for (int kk = 0; kk < 16; kk++) {
            float4 a = *(const float4*)&As[kk][ty * 4];
            float4 b = *(const float4*)&Bs[kk][tx * 4];
            float ar[4] = {a.x, a.y, a.z, a.w};
            float br[4] = {b.x, b.y, b.z, b.w};
            #pragma unroll
            for (int i = 0; i < 4; i++)
                #pragma unroll
                for (int j = 0; j < 4; j++)
                    acc[i][j] = fmaf(ar[i], br[j], acc[i][j]);
        }
        __syncthreads();
    }
    #pragma unroll
    for (int i = 0; i < 4; i++) {
        int m = m0 + ty * 4 + i;
        #pragma unroll
        for (int j = 0; j < 4; j++) {
            int n = n0 + tx * 4 + j;
            float v = fmaxf(acc[i][j] + bias[n], 0.f);
            C[(size_t)m * N + n] = v;
            C16[(size_t)m * N + n] = (f16)v;
        }
    }
}

// ---------------- fused GRU step: gh GEMM (fp16 MFMA) + gates + h update + decoder ----------------
// Block tile: 128 rows (m) x 64 embedding cols (e) x 3 gates. Grid (8, 32) = 256 blocks.
// 4 waves: wr = wid>>1 (64-row half), wc = wid&1 (32-col half). Wave frag: 2x(32 rows) x 3 gates.
__global__ __launch_bounds__(256) void gru_step(
    const f16* __restrict__ h16_in, const float* __restrict__ h32_in,
    f16* __restrict__ h16_out, float* __restrict__ h32_out,
    const f16* __restrict__ w16,          // [1536][512]
    const float* __restrict__ b_hh,
    const float* __restrict__ w_ih, const float* __restrict__ b_ih,
    const float* __restrict__ dec_w,
    float* __restrict__ out, int t)
{
    __shared__ __align__(16) f16 As[128 * LDSK];   // 18432 B
    __shared__ __align__(16) f16 Bs[192 * LDSK];   // 27648 B
    int tid  = threadIdx.x;
    int wid  = tid >> 6, lane = tid & 63;
    int wr   = wid >> 1, wc = wid & 1;
    int m0   = blockIdx.y * 128, e0 = blockIdx.x * 64;
    int col  = lane & 31, half = lane >> 5;

    f32x16 acc[3][2];
    #pragma unroll
    for (int g = 0; g < 3; g++)
        #pragma unroll
        for (int mi = 0; mi < 2; mi++)
            #pragma unroll
            for (int r = 0; r < 16; r++) acc[g][mi][r] = 0.f;

    for (int k0 = 0; k0 < EMB; k0 += 64) {
        // stage to regs (A: 128x64 = 1024 16B-chunks; B: 192x64 = 1536 chunks)
        float4 ra[4], rb[6];
        #pragma unroll
        for (int i = 0; i < 4; i++) {
            int q = i * 256 + tid, row = q >> 3, kc = q & 7;
            ra[i] = *(const float4*)(h16_in + (size_t)(m0 + row) * EMB + k0 + kc * 8);
        }
        #pragma unroll
        for (int i = 0; i < 6; i++) {
            int q = i * 256 + tid, r = q >> 3, kc = q & 7;
            int R = (r >> 6) * EMB + e0 + (r & 63);          // gate*512 + e
            rb[i] = *(const float4*)(w16 + (size_t)R * EMB + k0 + kc * 8);
        }
        __syncthreads();
        #pragma unroll
        for (int i = 0; i < 4; i++) {
            int q = i * 256 + tid, row = q >> 3, kc = q & 7;
            *(float4*)(As + row * LDSK + kc * 8) = ra[i];
        }
        #pragma unroll
        for (int i = 0; i < 6; i++) {
            int q = i * 256 + tid, r = q >> 3, kc = q & 7;
            *(float4*)(Bs + r * LDSK + kc * 8) = rb[i];
        }
        __syncthreads();
        #pragma unroll
        for (int kk = 0; kk < 4; kk++) {
            int koff = kk * 16 + half * 8;
            f16x8 af[2], bf[3];
            #pragma unroll
            for (int mi = 0; mi < 2; mi++)
                af[mi] = *(const f16x8*)(As + (wr * 64 + mi * 32 + col) * LDSK + koff);
            #pragma unroll
            for (int g = 0; g < 3; g++)
                bf[g] = *(const f16x8*)(Bs + (g * 64 + wc * 32 + col) * LDSK + koff);
            #pragma unroll
            for (int g = 0; g < 3; g++)
                #pragma unroll
                for (int mi = 0; mi < 2; mi++)
                    acc[g][mi] = __builtin_amdgcn_mfma_f32_32x32x16_f16(
                        af[mi], bf[g], acc[g][mi], 0, 0, 0);
        }
        __syncthreads();
    }

    // epilogue: gates + h update + decoder partial
    int e = e0 + wc * 32 + col;
    float wir = w_ih[e], wiz = w_ih[EMB + e], win = w_ih[2 * EMB + e];
    float bir = b_ih[e], biz = b_ih[EMB + e], bin_ = b_ih[2 * EMB + e];
    float bhr = b_hh[e], bhz = b_hh[EMB + e], bhn = b_hh[2 * EMB + e];
    float dw  = dec_w[e];

    #pragma unroll
    for (int mi = 0; mi < 2; mi++) {
        #pragma unroll
        for (int r = 0; r < 16; r++) {
            int m = m0 + wr * 64 + mi * 32 + (r & 3) + 8 * (r >> 2) + 4 * half;
            float prev = (t > 0) ? out[(size_t)m * TSTEP + (t - 1)] : 0.f;
            float gr  = acc[0][mi][r] + bhr + fmaf(prev, wir, bir);
            float gz  = acc[1][mi][r] + bhz + fmaf(prev, wiz, biz);
            float ghn = acc[2][mi][r] + bhn;
            float gin = fmaf(prev, win, bin_);
            float rr = sigmoid_fast(gr);
            float zz = sigmoid_fast(gz);
            float nn = tanh_fast(fmaf(rr, ghn, gin));
            float hp = h32_in[(size_t)m * EMB + e];
            float hn = fmaf(zz, hp - nn, nn);        // (1-z)n + z*hp
            h32_out[(size_t)m * EMB + e] = hn;
            h16_out[(size_t)m * EMB + e] = (f16)hn;
            float v = hn * dw;
            v += __shfl_xor(v, 1);  v += __shfl_xor(v, 2);
            v += __shfl_xor(v, 4);  v += __shfl_xor(v, 8);
            v += __shfl_xor(v, 16);
            if (col == 0) atomicAdd(&out[(size_t)m * TSTEP + t], v);
        }
    }
}

// ---------------- helpers ----------------
__global__ void cvt_w_kernel(const float* __restrict__ w, f16* __restrict__ o, int n) {
    int i = blockIdx.x * 256 + threadIdx.x;
    if (i < n) o[i] = (f16)w[i];
}
__global__ void init_out_kernel(float* __restrict__ out, const float* __restrict__ dec_b, int n) {
    int i = blockIdx.x * 256 + threadIdx.x;
    if (i < n) out[i] = dec_b[0];
}

extern "C" void kernel_launch(void* const* d_in, const int* in_sizes, int n_in,
                              void* d_out, int out_size, void* d_ws, size_t ws_size,
                              hipStream_t stream)
{
    const float* x      = (const float*)d_in[0];
    const float* conv_w = (const float*)d_in[1];
    const float* conv_b = (const float*)d_in[2];
    const float* fc_w   = (const float*)d_in[3];
    const float* fc_b   = (const float*)d_in[4];
    const float* w_ih   = (const float*)d_in[5];
    const float* b_ih   = (const float*)d_in[6];
    const float* w_hh   = (const float*)d_in[7];
    const float* b_hh   = (const float*)d_in[8];
    const float* dec_w  = (const float*)d_in[9];
    const float* dec_b  = (const float*)d_in[10];
    float* out = (float*)d_out;

    char* ws = (char*)d_ws;
    // layout (bytes):
    //   [0, 18874368)          convbuf fp32 [4096][1152]; after FC reused as:
    //     [0, 8388608)         h32_b
    //     [8388608, 12582912)  h16_b
    //   [18874368, 27262976)   h32_a
    //   [27262976, 31457280)   h16_a
    //   [31457280, 33030144)   w16 [1536][512] f16
    float* convbuf = (float*)ws;
    float* h32_b   = (float*)ws;
    f16*   h16_b   = (f16*)(ws + 8388608);
    float* h32_a   = (float*)(ws + 18874368);
    f16*   h16_a   = (f16*)(ws + 27262976);
    f16*   w16     = (f16*)(ws + 31457280);

    cvt_w_kernel<<<(G3 * EMB + 255) / 256, 256, 0, stream>>>(w_hh, w16, G3 * EMB);
    init_out_kernel<<<(B_ * TSTEP + 255) / 256, 256, 0, stream>>>(out, dec_b, B_ * TSTEP);

    conv_relu_kernel<<<B_ / 8, 256, 0, stream>>>(x, conv_w, conv_b, convbuf);
    gemm_bt_relu16<<<dim3(EMB / 64, B_ / 64), 256, 0, stream>>>(
        convbuf, fc_w, fc_b, h32_a, h16_a, B_, EMB, KFC);

    for (int t = 0; t < TSTEP; t++) {
        const f16*   hi16 = (t & 1) ? h16_b : h16_a;
        const float* hi32 = (t & 1) ? h32_b : h32_a;
        f16*   ho16 = (t & 1) ? h16_a : h16_b;
        float* ho32 = (t & 1) ? h32_a : h32_b;
        gru_step<<<dim3(EMB / 64, B_ / 128), 256, 0, stream>>>(
            hi16, hi32, ho16, ho32, w16, b_hh, w_ih, b_ih, dec_w, out, t);
    }
}

// Round 3
// 1713.586 us; speedup vs baseline: 3.1205x; 1.8652x over previous
//
#include <hip/hip_runtime.h>
#include <math.h>

#define B_    4096
#define CIN   60
#define CW    32
#define EMB   512
#define TSTEP 50
#define KFC   1152   // CW*6*6
#define G3    1536   // 3*EMB

typedef _Float16 f16;
typedef _Float16 f16x8 __attribute__((ext_vector_type(8)));
typedef float    f32x16 __attribute__((ext_vector_type(16)));

typedef __attribute__((address_space(3))) void       lds_void_t;
typedef __attribute__((address_space(1))) const void g_void_t;

__device__ __forceinline__ float sigmoid_fast(float x) { return 1.f / (1.f + __expf(-x)); }
__device__ __forceinline__ float tanh_fast(float x) {
    float e = __expf(2.f * x);
    return 1.f - 2.f / (e + 1.f);
}

// ---------------- conv 3x3 VALID + relu: 1 image per wave, grid 1024 ----------------
__global__ __launch_bounds__(256) void conv_relu_kernel(
    const float* __restrict__ x, const float* __restrict__ w,
    const float* __restrict__ bias, float* __restrict__ out)
{
    int wid = threadIdx.x >> 6, lane = threadIdx.x & 63;
    int b = blockIdx.x * 4 + wid;
    int oh = lane >> 3, ow = lane & 7;
    bool valid = (oh < 6) && (ow < 6);
    int pos = oh * 6 + ow;
    const float* xb = x + (size_t)b * (CIN * 64);

    float acc[CW];
    #pragma unroll
    for (int co = 0; co < CW; co++) acc[co] = bias[co];

    #pragma unroll 1
    for (int ci = 0; ci < CIN; ci++) {
        float xv = xb[ci * 64 + lane];              // coalesced 256B/wave
        float n0 = __shfl(xv, lane + 0,  64);
        float n1 = __shfl(xv, lane + 1,  64);
        float n2 = __shfl(xv, lane + 2,  64);
        float n3 = __shfl(xv, lane + 8,  64);
        float n4 = __shfl(xv, lane + 9,  64);
        float n5 = __shfl(xv, lane + 10, 64);
        float n6 = __shfl(xv, lane + 16, 64);
        float n7 = __shfl(xv, lane + 17, 64);
        float n8 = __shfl(xv, lane + 18, 64);
        #pragma unroll
        for (int co = 0; co < CW; co++) {
            const float* wp = w + (co * CIN + ci) * 9;   // wave-uniform -> s_load
            float s = acc[co];
            s = fmaf(n0, wp[0], s); s = fmaf(n1, wp[1], s); s = fmaf(n2, wp[2], s);
            s = fmaf(n3, wp[3], s); s = fmaf(n4, wp[4], s); s = fmaf(n5, wp[5], s);
            s = fmaf(n6, wp[6], s); s = fmaf(n7, wp[7], s); s = fmaf(n8, wp[8], s);
            acc[co] = s;
        }
    }
    if (valid) {
        float* ob = out + (size_t)b * KFC;
        #pragma unroll
        for (int co = 0; co < CW; co++)
            ob[co * 36 + pos] = fmaxf(acc[co], 0.f);
    }
}

// ---------------- fp32 GEMM C = A(MxK) * B(NxK)^T + bias, relu, + f16 copy ----------------
__global__ __launch_bounds__(256) void gemm_bt_relu16(
    const float* __restrict__ A, const float* __restrict__ Bm,
    const float* __restrict__ bias, float* __restrict__ C,
    f16* __restrict__ C16, int M, int N, int K)
{
    __shared__ __align__(16) float As[16][68];
    __shared__ __align__(16) float Bs[16][68];
    int m0 = blockIdx.y * 64, n0 = blockIdx.x * 64;
    int tid = threadIdx.x;
    int lr = tid >> 2, lc = tid & 3;
    int ty = tid >> 4, tx = tid & 15;
    float acc[4][4] = {};

    for (int k0 = 0; k0 < K; k0 += 16) {
        float4 av = *(const float4*)(A  + (size_t)(m0 + lr) * K + k0 + lc * 4);
        float4 bv = *(const float4*)(Bm + (size_t)(n0 + lr) * K + k0 + lc * 4);
        As[lc * 4 + 0][lr] = av.x; As[lc * 4 + 1][lr] = av.y;
        As[lc * 4 + 2][lr] = av.z; As[lc * 4 + 3][lr] = av.w;
        Bs[lc * 4 + 0][lr] = bv.x; Bs[lc * 4 + 1][lr] = bv.y;
        Bs[lc * 4 + 2][lr] = bv.z; Bs[lc * 4 + 3][lr] = bv.w;
        __syncthreads();
        #pragma unroll
        for (int kk = 0; kk < 16; kk++) {
            float4 a = *(const float4*)&As[kk][ty * 4];
            float4 b = *(const float4*)&Bs[kk][tx * 4];
            float ar[4] = {a.x, a.y, a.z, a.w};
            float br[4] = {b.x, b.y, b.z, b.w};
            #pragma unroll
            for (int i = 0; i < 4; i++)
                #pragma unroll
                for (int j = 0; j < 4; j++)
                    acc[i][j] = fmaf(ar[i], br[j], acc[i][j]);
        }
        __syncthreads();
    }
    #pragma unroll
    for (int i = 0; i < 4; i++) {
        int m = m0 + ty * 4 + i;
        #pragma unroll
        for (int j = 0; j < 4; j++) {
            int n = n0 + tx * 4 + j;
            float v = fmaxf(acc[i][j] + bias[n], 0.f);
            C[(size_t)m * N + n] = v;
            C16[(size_t)m * N + n] = (f16)v;
        }
    }
}

// ---------------- fused GRU step, 2-phase gload_lds pipeline ----------------
// Tile 64 rows x 64 e-cols x 3 gates. Grid 512 blocks (2/CU), 4 waves.
// Wave (wr,wc): 32 rows x 32 cols x 3 gates. XOR-swizzled LDS via pre-swizzled
// global source (gload_lds writes linearly) + swizzled ds_read.
__global__ __launch_bounds__(256) void gru_step(
    const f16* __restrict__ h16_in, const float* __restrict__ h32_in,
    f16* __restrict__ h16_out, float* __restrict__ h32_out,
    const f16* __restrict__ w16,          // [1536][512]
    const float* __restrict__ b_hh,
    const float* __restrict__ w_ih, const float* __restrict__ b_ih,
    const float* __restrict__ dec_w,
    float* __restrict__ out, int t)
{
    __shared__ __align__(16) f16 As[2][64 * 64];    // 2 x 8 KB
    __shared__ __align__(16) f16 Bs[2][192 * 64];   // 2 x 24 KB
    int tid = threadIdx.x, wid = tid >> 6, lane = tid & 63;
    int wr = wid >> 1, wc = wid & 1;
    int col = lane & 31, half = lane >> 5;

    // XCD-friendly swizzle: each XCD gets 8 m-groups x all 8 e-groups
    // -> per-XCD L2 set: full w16 (1.5MB) + h16 slice (0.5MB) + h32 slice.
    int flat = blockIdx.y * 8 + blockIdx.x;
    int swz  = (flat & 7) * 64 + (flat >> 3);
    int m0 = (swz >> 3) * 64, e0 = (swz & 7) * 64;

    // staging source addresses (pre-swizzled within each 128B row: chunk c = cp ^ (row&7))
    const f16* gA[2]; const f16* gB[6];
    #pragma unroll
    for (int a = 0; a < 2; a++) {
        int q = a * 256 + tid;
        int row = q >> 3, cp = q & 7, c = cp ^ (row & 7);
        gA[a] = h16_in + (size_t)(m0 + row) * EMB + c * 8;
    }
    #pragma unroll
    for (int bq = 0; bq < 6; bq++) {
        int q = bq * 256 + tid;
        int row = q >> 3, cp = q & 7, c = cp ^ (row & 7);
        int R = (row >> 6) * EMB + e0 + (row & 63);      // gate*512 + e
        gB[bq] = w16 + (size_t)R * EMB + c * 8;
    }

    auto stage = [&](int buf, int k0) {
        #pragma unroll
        for (int a = 0; a < 2; a++)
            __builtin_amdgcn_global_load_lds(
                (const g_void_t*)(gA[a] + k0),
                (lds_void_t*)(&As[buf][0] + (size_t)(a * 256 + wid * 64) * 8),
                16, 0, 0);
        #pragma unroll
        for (int bq = 0; bq < 6; bq++)
            __builtin_amdgcn_global_load_lds(
                (const g_void_t*)(gB[bq] + k0),
                (lds_void_t*)(&Bs[buf][0] + (size_t)(bq * 256 + wid * 64) * 8),
                16, 0, 0);
    };

    f32x16 acc[3];
    #pragma unroll
    for (int g = 0; g < 3; g++)
        #pragma unroll
        for (int r = 0; r < 16; r++) acc[g][r] = 0.f;

    stage(0, 0);
    __syncthreads();                       // vmcnt(0) drain + barrier

    int arow = wr * 32 + col;
    int cur = 0;
    #pragma unroll 1
    for (int k = 0; k < 8; k++) {
        if (k < 7) stage(cur ^ 1, (k + 1) * 64);   // prefetch next K-tile
        __builtin_amdgcn_s_setprio(1);
        #pragma unroll
        for (int kk = 0; kk < 4; kk++) {
            int ch = kk * 2 + half;
            f16x8 af = *(const f16x8*)&As[cur][arow * 64 + ((ch ^ (arow & 7)) << 3)];
            #pragma unroll
            for (int g = 0; g < 3; g++) {
                int br = g * 64 + wc * 32 + col;
                f16x8 bf = *(const f16x8*)&Bs[cur][br * 64 + ((ch ^ (br & 7)) << 3)];
                acc[g] = __builtin_amdgcn_mfma_f32_32x32x16_f16(af, bf, acc[g], 0, 0, 0);
            }
        }
        __builtin_amdgcn_s_setprio(0);
        __syncthreads();                   // drains vmcnt(0): next buf ready
        cur ^= 1;
    }

    // epilogue: gates + h update + decoder partial
    int e = e0 + wc * 32 + col;
    float wir = w_ih[e], wiz = w_ih[EMB + e], win = w_ih[2 * EMB + e];
    float bir = b_ih[e], biz = b_ih[EMB + e], bin_ = b_ih[2 * EMB + e];
    float bhr = b_hh[e], bhz = b_hh[EMB + e], bhn = b_hh[2 * EMB + e];
    float dw  = dec_w[e];

    #pragma unroll
    for (int r = 0; r < 16; r++) {
        int m = m0 + wr * 32 + (r & 3) + 8 * (r >> 2) + 4 * half;
        float prev = (t > 0) ? out[(size_t)m * TSTEP + (t - 1)] : 0.f;
        float gr  = acc[0][r] + bhr + fmaf(prev, wir, bir);
        float gz  = acc[1][r] + bhz + fmaf(prev, wiz, biz);
        float ghn = acc[2][r] + bhn;
        float gin = fmaf(prev, win, bin_);
        float rr = sigmoid_fast(gr);
        float zz = sigmoid_fast(gz);
        float nn = tanh_fast(fmaf(rr, ghn, gin));
        float hp = h32_in[(size_t)m * EMB + e];
        float hn = fmaf(zz, hp - nn, nn);            // (1-z)n + z*hp
        h32_out[(size_t)m * EMB + e] = hn;
        h16_out[(size_t)m * EMB + e] = (f16)hn;
        float v = hn * dw;
        v += __shfl_xor(v, 1);  v += __shfl_xor(v, 2);
        v += __shfl_xor(v, 4);  v += __shfl_xor(v, 8);
        v += __shfl_xor(v, 16);
        if (col == 0) atomicAdd(&out[(size_t)m * TSTEP + t], v);
    }
}

// ---------------- helpers ----------------
__global__ void cvt_w_kernel(const float* __restrict__ w, f16* __restrict__ o, int n) {
    int i = blockIdx.x * 256 + threadIdx.x;
    if (i < n) o[i] = (f16)w[i];
}
__global__ void init_out_kernel(float* __restrict__ out, const float* __restrict__ dec_b, int n) {
    int i = blockIdx.x * 256 + threadIdx.x;
    if (i < n) out[i] = dec_b[0];
}

extern "C" void kernel_launch(void* const* d_in, const int* in_sizes, int n_in,
                              void* d_out, int out_size, void* d_ws, size_t ws_size,
                              hipStream_t stream)
{
    const float* x      = (const float*)d_in[0];
    const float* conv_w = (const float*)d_in[1];
    const float* conv_b = (const float*)d_in[2];
    const float* fc_w   = (const float*)d_in[3];
    const float* fc_b   = (const float*)d_in[4];
    const float* w_ih   = (const float*)d_in[5];
    const float* b_ih   = (const float*)d_in[6];
    const float* w_hh   = (const float*)d_in[7];
    const float* b_hh   = (const float*)d_in[8];
    const float* dec_w  = (const float*)d_in[9];
    const float* dec_b  = (const float*)d_in[10];
    float* out = (float*)d_out;

    char* ws = (char*)d_ws;
    // layout (bytes):
    //   [0, 18874368)          convbuf fp32 [4096][1152]; after FC reused as:
    //     [0, 8388608)         h32_b
    //     [8388608, 12582912)  h16_b
    //   [18874368, 27262976)   h32_a
    //   [27262976, 31457280)   h16_a
    //   [31457280, 33030144)   w16 [1536][512] f16
    float* convbuf = (float*)ws;
    float* h32_b   = (float*)ws;
    f16*   h16_b   = (f16*)(ws + 8388608);
    float* h32_a   = (float*)(ws + 18874368);
    f16*   h16_a   = (f16*)(ws + 27262976);
    f16*   w16     = (f16*)(ws + 31457280);

    cvt_w_kernel<<<(G3 * EMB + 255) / 256, 256, 0, stream>>>(w_hh, w16, G3 * EMB);
    init_out_kernel<<<(B_ * TSTEP + 255) / 256, 256, 0, stream>>>(out, dec_b, B_ * TSTEP);

    conv_relu_kernel<<<B_ / 4, 256, 0, stream>>>(x, conv_w, conv_b, convbuf);
    gemm_bt_relu16<<<dim3(EMB / 64, B_ / 64), 256, 0, stream>>>(
        convbuf, fc_w, fc_b, h32_a, h16_a, B_, EMB, KFC);

    for (int t = 0; t < TSTEP; t++) {
        const f16*   hi16 = (t & 1) ? h16_b : h16_a;
        const float* hi32 = (t & 1) ? h32_b : h32_a;
        f16*   ho16 = (t & 1) ? h16_a : h16_b;
        float* ho32 = (t & 1) ? h32_a : h32_b;
        gru_step<<<dim3(8, B_ / 64), 256, 0, stream>>>(
            hi16, hi32, ho16, ho32, w16, b_hh, w_ih, b_ih, dec_w, out, t);
    }
}

// Round 4
// 1357.048 us; speedup vs baseline: 3.9403x; 1.2627x over previous
//
#include <hip/hip_runtime.h>
#include <math.h>

#define B_    4096
#define CIN   60
#define CW    32
#define EMB   512
#define TSTEP 50
#define KFC   1152   // 36*32 (pos-major, co-minor layout!)
#define G3    1536

typedef _Float16 f16;
typedef _Float16 f16x4 __attribute__((ext_vector_type(4)));
typedef _Float16 f16x8 __attribute__((ext_vector_type(8)));
typedef float    f32x4 __attribute__((ext_vector_type(4)));
typedef float    f32x16 __attribute__((ext_vector_type(16)));

typedef __attribute__((address_space(3))) void       lds_void_t;
typedef __attribute__((address_space(1))) const void g_void_t;

__device__ __forceinline__ float sigmoid_fast(float x){ return 1.f/(1.f+__expf(-x)); }
__device__ __forceinline__ float tanh_fast(float x){ float e=__expf(2.f*x); return 1.f-2.f/(e+1.f); }

// ---------- weight prep kernels ----------
__global__ void cvt_whh_kernel(const float* __restrict__ w, f16* __restrict__ o, int n) {
    int i = blockIdx.x * 256 + threadIdx.x;
    if (i < n) o[i] = (f16)w[i];
}
// conv_w [32][60][3][3] -> w16c [9 khkw][32 co][64 ci padded], chunk-XOR(co&7) swizzled
__global__ void cvt_convw_kernel(const float* __restrict__ w, f16* __restrict__ o) {
    int i = blockIdx.x * 256 + threadIdx.x;           // 18432
    if (i >= 9 * 32 * 64) return;
    int khkw = i >> 11, r = i & 2047, co = r >> 6, ci = r & 63;
    float v = (ci < CIN) ? w[(co * CIN + ci) * 9 + khkw] : 0.f;
    int dst = khkw * 2048 + co * 64 + (((ci >> 3) ^ (co & 7)) << 3) + (ci & 7);
    o[dst] = (f16)v;
}
// fc_w [512][co*36+pos] -> fcp16 [512][pos*32+co] f16
__global__ void cvt_fcw_kernel(const float* __restrict__ w, f16* __restrict__ o) {
    int i = blockIdx.x * 256 + threadIdx.x;           // 512*1152
    if (i >= EMB * KFC) return;
    int e = i / KFC, j = i % KFC;
    int co = j & 31, pos = j >> 5;
    o[i] = (f16)w[e * KFC + co * 36 + pos];
}
__global__ void init_out_kernel(float* __restrict__ out, const float* __restrict__ dec_b, int n) {
    int i = blockIdx.x * 256 + threadIdx.x;
    if (i < n) out[i] = dec_b[0];
}

// ---------- conv 3x3 VALID + relu via im2col MFMA ----------
// block = 8 images, 256 thr. xt LDS [img][px 64][ci 64pad] f16, chunk-XOR(px&7).
// M = 288 rows (img*36+pos) = 18 tiles; N = 32 co = 2 tiles; K = 9*64 = 18 k-steps of 32.
__global__ __launch_bounds__(256) void conv_mfma(
    const float* __restrict__ x, const f16* __restrict__ w16c,
    const float* __restrict__ conv_b, f16* __restrict__ outc)
{
    __shared__ __align__(16) f16 xt[8 * 64 * 64];    // 64 KB
    __shared__ __align__(16) f16 ws16[9 * 32 * 64];  // 36 KB
    int tid = threadIdx.x, wid = tid >> 6, lane = tid & 63;
    int b0 = blockIdx.x * 8;

    #pragma unroll
    for (int i = 0; i < 9; i++)
        __builtin_amdgcn_global_load_lds(
            (const g_void_t*)(w16c + (i * 256 + tid) * 8),
            (lds_void_t*)((char*)ws16 + (i * 256 + wid * 64) * 16), 16, 0, 0);

    #pragma unroll 1
    for (int it = 0; it < 30; it++) {
        int idx = it * 4 + wid;                       // 0..119 = img*15+cq
        int img = idx / 15, cq = idx % 15;
        const float* xp = x + ((size_t)(b0 + img) * CIN + cq * 4) * 64 + lane;
        f16x4 v = { (f16)xp[0], (f16)xp[64], (f16)xp[128], (f16)xp[192] };
        int off = img * 8192 + lane * 128 + (((cq >> 1) ^ (lane & 7)) << 4) + (cq & 1) * 8;
        *(f16x4*)((char*)xt + off) = v;
    }
    #pragma unroll
    for (int i = 0; i < 2; i++) {                     // zero-pad ci 60..63
        int s = i * 256 + tid, img = s >> 6, px = s & 63;
        int off = img * 8192 + px * 128 + ((7 ^ (px & 7)) << 4) + 8;
        *(f16x4*)((char*)xt + off) = f16x4{0, 0, 0, 0};
    }
    __syncthreads();

    int mhalf = wid >> 1, nt = wid & 1;
    int lrow = lane & 15, kgrp = lane >> 4;
    int co = nt * 16 + lrow;

    int imgs[9], pxb[9];
    #pragma unroll
    for (int i = 0; i < 9; i++) {
        int row = mhalf * 144 + i * 16 + lrow;
        int img = (row * 1821) >> 16, pos = row - img * 36;
        int oh = (pos * 43) >> 8, ow = pos - oh * 6;
        imgs[i] = img; pxb[i] = oh * 8 + ow;
    }

    f32x4 acc[9];
    #pragma unroll
    for (int i = 0; i < 9; i++) acc[i] = f32x4{0, 0, 0, 0};

    #pragma unroll 1
    for (int ks = 0; ks < 18; ks++) {
        int khkw = ks >> 1;
        int kh = (khkw * 86) >> 8, kw = khkw - kh * 3;
        int c = (ks & 1) * 4 + kgrp;
        f16x8 bf = *(const f16x8*)((const char*)ws16 +
                     khkw * 4096 + co * 128 + ((c ^ (co & 7)) << 4));
        #pragma unroll
        for (int i = 0; i < 9; i++) {
            int px = pxb[i] + kh * 8 + kw;
            f16x8 af = *(const f16x8*)((const char*)xt +
                         imgs[i] * 8192 + px * 128 + ((c ^ (px & 7)) << 4));
            acc[i] = __builtin_amdgcn_mfma_f32_16x16x32_f16(af, bf, acc[i], 0, 0, 0);
        }
    }

    float cb = conv_b[co];
    #pragma unroll
    for (int i = 0; i < 9; i++) {
        #pragma unroll
        for (int j = 0; j < 4; j++) {
            int row = mhalf * 144 + i * 16 + kgrp * 4 + j;
            int img = (row * 1821) >> 16, pos = row - img * 36;
            float v = fmaxf(acc[i][j] + cb, 0.f);
            outc[(size_t)(b0 + img) * KFC + pos * 32 + co] = (f16)v;
        }
    }
}

// ---------- FC: f16 MFMA GEMM, C = A(4096x1152) * B(512x1152)^T, relu -> h16 ----------
__global__ __launch_bounds__(256) void fc_mfma(
    const f16* __restrict__ A, const f16* __restrict__ Bm,
    const float* __restrict__ bias, f16* __restrict__ h16)
{
    __shared__ __align__(16) f16 As[2][64 * 64];
    __shared__ __align__(16) f16 Bs[2][64 * 64];
    int tid = threadIdx.x, wid = tid >> 6, lane = tid & 63;
    int wr = wid >> 1, wc = wid & 1;
    int col = lane & 31, half = lane >> 5;
    int m0 = blockIdx.y * 64, n0 = blockIdx.x * 64;

    const f16* gA[2]; const f16* gB[2];
    #pragma unroll
    for (int i = 0; i < 2; i++) {
        int q = i * 256 + tid, row = q >> 3, cp = q & 7, c = cp ^ (row & 7);
        gA[i] = A  + (size_t)(m0 + row) * KFC + c * 8;
        gB[i] = Bm + (size_t)(n0 + row) * KFC + c * 8;
    }
    auto stage = [&](int buf, int k0) {
        #pragma unroll
        for (int i = 0; i < 2; i++)
            __builtin_amdgcn_global_load_lds((const g_void_t*)(gA[i] + k0),
                (lds_void_t*)((char*)&As[buf][0] + (i * 256 + wid * 64) * 16), 16, 0, 0);
        #pragma unroll
        for (int i = 0; i < 2; i++)
            __builtin_amdgcn_global_load_lds((const g_void_t*)(gB[i] + k0),
                (lds_void_t*)((char*)&Bs[buf][0] + (i * 256 + wid * 64) * 16), 16, 0, 0);
    };

    f32x16 acc;
    #pragma unroll
    for (int r = 0; r < 16; r++) acc[r] = 0.f;

    stage(0, 0); stage(1, 64);
    int cur = 0, arow = wr * 32 + col, brow = wc * 32 + col;
    #pragma unroll 1
    for (int kt = 0; kt < 17; kt++) {
        asm volatile("s_waitcnt vmcnt(4)" ::: "memory");
        __builtin_amdgcn_s_barrier();
        __builtin_amdgcn_sched_barrier(0);
        __builtin_amdgcn_s_setprio(1);
        #pragma unroll
        for (int kk = 0; kk < 4; kk++) {
            int ch = kk * 2 + half;
            f16x8 af = *(const f16x8*)&As[cur][arow * 64 + ((ch ^ (arow & 7)) << 3)];
            f16x8 bf = *(const f16x8*)&Bs[cur][brow * 64 + ((ch ^ (brow & 7)) << 3)];
            acc = __builtin_amdgcn_mfma_f32_32x32x16_f16(af, bf, acc, 0, 0, 0);
        }
        __builtin_amdgcn_s_setprio(0);
        __builtin_amdgcn_sched_barrier(0);
        __builtin_amdgcn_s_barrier();
        if (kt < 16) stage(cur, (kt + 2) * 64);
        cur ^= 1;
    }
    asm volatile("s_waitcnt vmcnt(0)" ::: "memory");
    __builtin_amdgcn_s_barrier();
    __builtin_amdgcn_sched_barrier(0);
    #pragma unroll
    for (int kk = 0; kk < 4; kk++) {
        int ch = kk * 2 + half;
        f16x8 af = *(const f16x8*)&As[cur][arow * 64 + ((ch ^ (arow & 7)) << 3)];
        f16x8 bf = *(const f16x8*)&Bs[cur][brow * 64 + ((ch ^ (brow & 7)) << 3)];
        acc = __builtin_amdgcn_mfma_f32_32x32x16_f16(af, bf, acc, 0, 0, 0);
    }

    #pragma unroll
    for (int r = 0; r < 16; r++) {
        int m = m0 + wr * 32 + (r & 3) + 8 * (r >> 2) + 4 * half;
        int n = n0 + wc * 32 + col;
        float v = fmaxf(acc[r] + bias[n], 0.f);
        h16[(size_t)m * EMB + n] = (f16)v;
    }
}

// ---------- fused GRU step: counted-vmcnt 2-buffer pipeline, f16-only h ----------
__global__ __launch_bounds__(256) void gru_step(
    const f16* __restrict__ h16_in, f16* __restrict__ h16_out,
    const f16* __restrict__ w16,          // [1536][512]
    const float* __restrict__ b_hh,
    const float* __restrict__ w_ih, const float* __restrict__ b_ih,
    const float* __restrict__ dec_w,
    float* __restrict__ out, int t)
{
    __shared__ __align__(16) f16 As[2][64 * 64];    // 2 x 8 KB
    __shared__ __align__(16) f16 Bs[2][192 * 64];   // 2 x 24 KB
    int tid = threadIdx.x, wid = tid >> 6, lane = tid & 63;
    int wr = wid >> 1, wc = wid & 1;
    int col = lane & 31, half = lane >> 5;

    int flat = blockIdx.y * 8 + blockIdx.x;
    int swz  = (flat & 7) * 64 + (flat >> 3);
    int m0 = (swz >> 3) * 64, e0 = (swz & 7) * 64;

    const f16* gA[2]; const f16* gB[6];
    #pragma unroll
    for (int a = 0; a < 2; a++) {
        int q = a * 256 + tid, row = q >> 3, cp = q & 7, c = cp ^ (row & 7);
        gA[a] = h16_in + (size_t)(m0 + row) * EMB + c * 8;
    }
    #pragma unroll
    for (int bq = 0; bq < 6; bq++) {
        int q = bq * 256 + tid, row = q >> 3, cp = q & 7, c = cp ^ (row & 7);
        int R = (row >> 6) * EMB + e0 + (row & 63);
        gB[bq] = w16 + (size_t)R * EMB + c * 8;
    }
    auto stage = [&](int buf, int k0) {
        #pragma unroll
        for (int a = 0; a < 2; a++)
            __builtin_amdgcn_global_load_lds((const g_void_t*)(gA[a] + k0),
                (lds_void_t*)((char*)&As[buf][0] + (a * 256 + wid * 64) * 16), 16, 0, 0);
        #pragma unroll
        for (int bq = 0; bq < 6; bq++)
            __builtin_amdgcn_global_load_lds((const g_void_t*)(gB[bq] + k0),
                (lds_void_t*)((char*)&Bs[buf][0] + (bq * 256 + wid * 64) * 16), 16, 0, 0);
    };

    f32x16 acc[3];
    #pragma unroll
    for (int g = 0; g < 3; g++)
        #pragma unroll
        for (int r = 0; r < 16; r++) acc[g][r] = 0.f;

    stage(0, 0); stage(1, 64);
    int cur = 0, arow = wr * 32 + col;
    #pragma unroll 1
    for (int kt = 0; kt < 7; kt++) {
        asm volatile("s_waitcnt vmcnt(8)" ::: "memory");
        __builtin_amdgcn_s_barrier();
        __builtin_amdgcn_sched_barrier(0);
        __builtin_amdgcn_s_setprio(1);
        #pragma unroll
        for (int kk = 0; kk < 4; kk++) {
            int ch = kk * 2 + half;
            f16x8 af = *(const f16x8*)&As[cur][arow * 64 + ((ch ^ (arow & 7)) << 3)];
            #pragma unroll
            for (int g = 0; g < 3; g++) {
                int br = g * 64 + wc * 32 + col;
                f16x8 bf = *(const f16x8*)&Bs[cur][br * 64 + ((ch ^ (br & 7)) << 3)];
                acc[g] = __builtin_amdgcn_mfma_f32_32x32x16_f16(af, bf, acc[g], 0, 0, 0);
            }
        }
        __builtin_amdgcn_s_setprio(0);
        __builtin_amdgcn_sched_barrier(0);
        __builtin_amdgcn_s_barrier();
        if (kt < 6) stage(cur, (kt + 2) * 64);
        cur ^= 1;
    }
    asm volatile("s_waitcnt vmcnt(0)" ::: "memory");
    __builtin_amdgcn_s_barrier();
    __builtin_amdgcn_sched_barrier(0);
    #pragma unroll
    for (int kk = 0; kk < 4; kk++) {
        int ch = kk * 2 + half;
        f16x8 af = *(const f16x8*)&As[cur][arow * 64 + ((ch ^ (arow & 7)) << 3)];
        #pragma unroll
        for (int g = 0; g < 3; g++) {
            int br = g * 64 + wc * 32 + col;
            f16x8 bf = *(const f16x8*)&Bs[cur][br * 64 + ((ch ^ (br & 7)) << 3)];
            acc[g] = __builtin_amdgcn_mfma_f32_32x32x16_f16(af, bf, acc[g], 0, 0, 0);
        }
    }

    int e = e0 + wc * 32 + col;
    float wir = w_ih[e], wiz = w_ih[EMB + e], win = w_ih[2 * EMB + e];
    float bir = b_ih[e], biz = b_ih[EMB + e], bin_ = b_ih[2 * EMB + e];
    float bhr = b_hh[e], bhz = b_hh[EMB + e], bhn = b_hh[2 * EMB + e];
    float dw  = dec_w[e];

    #pragma unroll
    for (int r = 0; r < 16; r++) {
        int m = m0 + wr * 32 + (r & 3) + 8 * (r >> 2) + 4 * half;
        float prev = (t > 0) ? out[(size_t)m * TSTEP + (t - 1)] : 0.f;
        float gr  = acc[0][r] + bhr + fmaf(prev, wir, bir);
        float gz  = acc[1][r] + bhz + fmaf(prev, wiz, biz);
        float ghn = acc[2][r] + bhn;
        float gin = fmaf(prev, win, bin_);
        float rr = sigmoid_fast(gr);
        float zz = sigmoid_fast(gz);
        float nn = tanh_fast(fmaf(rr, ghn, gin));
        float hp = (float)h16_in[(size_t)m * EMB + e];
        float hn = fmaf(zz, hp - nn, nn);
        h16_out[(size_t)m * EMB + e] = (f16)hn;
        float v = hn * dw;
        v += __shfl_xor(v, 1);  v += __shfl_xor(v, 2);
        v += __shfl_xor(v, 4);  v += __shfl_xor(v, 8);
        v += __shfl_xor(v, 16);
        if (col == 0) atomicAdd(&out[(size_t)m * TSTEP + t], v);
    }
}

extern "C" void kernel_launch(void* const* d_in, const int* in_sizes, int n_in,
                              void* d_out, int out_size, void* d_ws, size_t ws_size,
                              hipStream_t stream)
{
    const float* x      = (const float*)d_in[0];
    const float* conv_w = (const float*)d_in[1];
    const float* conv_b = (const float*)d_in[2];
    const float* fc_w   = (const float*)d_in[3];
    const float* fc_b   = (const float*)d_in[4];
    const float* w_ih   = (const float*)d_in[5];
    const float* b_ih   = (const float*)d_in[6];
    const float* w_hh   = (const float*)d_in[7];
    const float* b_hh   = (const float*)d_in[8];
    const float* dec_w  = (const float*)d_in[9];
    const float* dec_b  = (const float*)d_in[10];
    float* out = (float*)d_out;

    char* ws = (char*)d_ws;
    // layout (bytes):
    //   [0,         9437184)   convbuf16 [4096][1152] f16 (pos*32+co order)
    //   [9437184,  13631488)   h16_a [4096][512]
    //   [13631488, 17825792)   h16_b [4096][512]
    //   [17825792, 19398656)   w16   [1536][512]
    //   [19398656, 19435520)   w16c  [9][32][64] swizzled
    //   [19435520, 20615168)   fcp16 [512][1152] permuted
    f16*   convbuf16 = (f16*)ws;
    f16*   h16_a     = (f16*)(ws + 9437184);
    f16*   h16_b     = (f16*)(ws + 13631488);
    f16*   w16       = (f16*)(ws + 17825792);
    f16*   w16c      = (f16*)(ws + 19398656);
    f16*   fcp16     = (f16*)(ws + 19435520);

    cvt_whh_kernel<<<(G3 * EMB + 255) / 256, 256, 0, stream>>>(w_hh, w16, G3 * EMB);
    cvt_convw_kernel<<<(9 * 32 * 64 + 255) / 256, 256, 0, stream>>>(conv_w, w16c);
    cvt_fcw_kernel<<<(EMB * KFC + 255) / 256, 256, 0, stream>>>(fc_w, fcp16);
    init_out_kernel<<<(B_ * TSTEP + 255) / 256, 256, 0, stream>>>(out, dec_b, B_ * TSTEP);

    conv_mfma<<<B_ / 8, 256, 0, stream>>>(x, w16c, conv_b, convbuf16);
    fc_mfma<<<dim3(EMB / 64, B_ / 64), 256, 0, stream>>>(convbuf16, fcp16, fc_b, h16_a);

    for (int t = 0; t < TSTEP; t++) {
        const f16* hi = (t & 1) ? h16_b : h16_a;
        f16*       ho = (t & 1) ? h16_a : h16_b;
        gru_step<<<dim3(8, B_ / 64), 256, 0, stream>>>(
            hi, ho, w16, b_hh, w_ih, b_ih, dec_w, out, t);
    }
}

// Round 5
// 779.087 us; speedup vs baseline: 6.8634x; 1.7418x over previous
//
#include <hip/hip_runtime.h>
#include <math.h>

#define B_    4096
#define CIN   60
#define CW    32
#define EMB   512
#define TSTEP 50
#define KFC   1152   // 36*32 (pos-major, co-minor layout!)
#define G3    1536

typedef _Float16 f16;
typedef _Float16 f16x4 __attribute__((ext_vector_type(4)));
typedef _Float16 f16x8 __attribute__((ext_vector_type(8)));
typedef float    f32x4 __attribute__((ext_vector_type(4)));
typedef float    f32x16 __attribute__((ext_vector_type(16)));

typedef __attribute__((address_space(3))) void       lds_void_t;
typedef __attribute__((address_space(1))) const void g_void_t;

__device__ __forceinline__ float sigmoid_fast(float x){ return 1.f/(1.f+__expf(-x)); }
__device__ __forceinline__ float tanh_fast(float x){ float e=__expf(2.f*x); return 1.f-2.f/(e+1.f); }

// ---------- fused weight prep: w_hh->f16, conv_w swizzle, fc_w permute, out init ----------
__global__ void prep_kernel(const float* __restrict__ w_hh, f16* __restrict__ w16,
                            const float* __restrict__ conv_w, f16* __restrict__ w16c,
                            const float* __restrict__ fc_w, f16* __restrict__ fcp16,
                            const float* __restrict__ dec_b, float* __restrict__ out)
{
    int i = blockIdx.x * 256 + threadIdx.x;
    if (i < G3 * EMB) { w16[i] = (f16)w_hh[i]; return; }
    i -= G3 * EMB;
    if (i < 9 * 32 * 64) {
        int khkw = i >> 11, r = i & 2047, co = r >> 6, ci = r & 63;
        float v = (ci < CIN) ? conv_w[(co * CIN + ci) * 9 + khkw] : 0.f;
        int dst = khkw * 2048 + co * 64 + (((ci >> 3) ^ (co & 7)) << 3) + (ci & 7);
        w16c[dst] = (f16)v;
        return;
    }
    i -= 9 * 32 * 64;
    if (i < EMB * KFC) {
        int e = i / KFC, j = i % KFC;
        int co = j & 31, pos = j >> 5;
        fcp16[i] = (f16)fc_w[e * KFC + co * 36 + pos];
        return;
    }
    i -= EMB * KFC;
    if (i < B_ * TSTEP) out[i] = dec_b[0];
}

// ---------- conv 3x3 VALID + relu via im2col MFMA, weights in registers ----------
// block = 8 images, 256 thr, xt LDS 64KB (2 blocks/CU).
__global__ __launch_bounds__(256) void conv_mfma(
    const float* __restrict__ x, const f16* __restrict__ w16c,
    const float* __restrict__ conv_b, f16* __restrict__ outc)
{
    __shared__ __align__(16) f16 xt[8 * 64 * 64];    // 64 KB
    int tid = threadIdx.x, wid = tid >> 6, lane = tid & 63;
    int b0 = blockIdx.x * 8;
    int mhalf = wid >> 1, nt = wid & 1;
    int lrow = lane & 15, kgrp = lane >> 4;
    int co = nt * 16 + lrow;

    // B-fragments straight to registers (w16c is 36KB, L2-hot)
    f16x8 bfr[18];
    #pragma unroll
    for (int ks = 0; ks < 18; ks++) {
        int khkw = ks >> 1, c = (ks & 1) * 4 + kgrp;
        bfr[ks] = *(const f16x8*)((const char*)w16c +
                    khkw * 4096 + co * 128 + ((c ^ (co & 7)) << 4));
    }
    float cb = conv_b[co];

    // stage x -> xt in 3 batches of 10 independent load groups
    #pragma unroll
    for (int bt = 0; bt < 3; bt++) {
        float ra[10][4];
        #pragma unroll
        for (int j = 0; j < 10; j++) {
            int idx = (bt * 10 + j) * 4 + wid;           // img*15 + cq
            int img = idx / 15, cq = idx - img * 15;
            const float* xp = x + ((size_t)(b0 + img) * CIN + cq * 4) * 64 + lane;
            ra[j][0] = xp[0]; ra[j][1] = xp[64]; ra[j][2] = xp[128]; ra[j][3] = xp[192];
        }
        #pragma unroll
        for (int j = 0; j < 10; j++) {
            int idx = (bt * 10 + j) * 4 + wid;
            int img = idx / 15, cq = idx - img * 15;
            f16x4 v = { (f16)ra[j][0], (f16)ra[j][1], (f16)ra[j][2], (f16)ra[j][3] };
            int off = img * 8192 + lane * 128 + (((cq >> 1) ^ (lane & 7)) << 4) + (cq & 1) * 8;
            *(f16x4*)((char*)xt + off) = v;
        }
    }
    #pragma unroll
    for (int i = 0; i < 2; i++) {                        // zero-pad ci 60..63
        int s = i * 256 + tid, img = s >> 6, px = s & 63;
        int off = img * 8192 + px * 128 + ((7 ^ (px & 7)) << 4) + 8;
        *(f16x4*)((char*)xt + off) = f16x4{0, 0, 0, 0};
    }
    __syncthreads();

    int imgs[9], pxb[9];
    #pragma unroll
    for (int i = 0; i < 9; i++) {
        int row = mhalf * 144 + i * 16 + lrow;
        int img = (row * 1821) >> 16, pos = row - img * 36;
        int oh = (pos * 43) >> 8, ow = pos - oh * 6;
        imgs[i] = img; pxb[i] = oh * 8 + ow;
    }

    f32x4 acc[9];
    #pragma unroll
    for (int i = 0; i < 9; i++) acc[i] = f32x4{0, 0, 0, 0};

    #pragma unroll
    for (int ks = 0; ks < 18; ks++) {                    // full unroll: static bfr index
        int khkw = ks >> 1;
        int kh = khkw / 3, kw = khkw - kh * 3;
        int c = (ks & 1) * 4 + kgrp;
        #pragma unroll
        for (int i = 0; i < 9; i++) {
            int px = pxb[i] + kh * 8 + kw;
            f16x8 af = *(const f16x8*)((const char*)xt +
                         imgs[i] * 8192 + px * 128 + ((c ^ (px & 7)) << 4));
            acc[i] = __builtin_amdgcn_mfma_f32_16x16x32_f16(af, bfr[ks], acc[i], 0, 0, 0);
        }
    }

    #pragma unroll
    for (int i = 0; i < 9; i++) {
        #pragma unroll
        for (int j = 0; j < 4; j++) {
            int row = mhalf * 144 + i * 16 + kgrp * 4 + j;
            int img = (row * 1821) >> 16, pos = row - img * 36;
            float v = fmaxf(acc[i][j] + cb, 0.f);
            outc[(size_t)(b0 + img) * KFC + pos * 32 + co] = (f16)v;
        }
    }
}

// ---------- FC: f16 MFMA GEMM, C = A(4096x1152) * B(512x1152)^T, relu -> h16 ----------
__global__ __launch_bounds__(256) void fc_mfma(
    const f16* __restrict__ A, const f16* __restrict__ Bm,
    const float* __restrict__ bias, f16* __restrict__ h16)
{
    __shared__ __align__(16) f16 As[2][64 * 64];
    __shared__ __align__(16) f16 Bs[2][64 * 64];
    int tid = threadIdx.x, wid = tid >> 6, lane = tid & 63;
    int wr = wid >> 1, wc = wid & 1;
    int col = lane & 31, half = lane >> 5;
    int m0 = blockIdx.y * 64, n0 = blockIdx.x * 64;

    const f16* gA[2]; const f16* gB[2];
    #pragma unroll
    for (int i = 0; i < 2; i++) {
        int q = i * 256 + tid, row = q >> 3, cp = q & 7, c = cp ^ (row & 7);
        gA[i] = A  + (size_t)(m0 + row) * KFC + c * 8;
        gB[i] = Bm + (size_t)(n0 + row) * KFC + c * 8;
    }
    auto stage = [&](int buf, int k0) {
        #pragma unroll
        for (int i = 0; i < 2; i++)
            __builtin_amdgcn_global_load_lds((const g_void_t*)(gA[i] + k0),
                (lds_void_t*)((char*)&As[buf][0] + (i * 256 + wid * 64) * 16), 16, 0, 0);
        #pragma unroll
        for (int i = 0; i < 2; i++)
            __builtin_amdgcn_global_load_lds((const g_void_t*)(gB[i] + k0),
                (lds_void_t*)((char*)&Bs[buf][0] + (i * 256 + wid * 64) * 16), 16, 0, 0);
    };

    f32x16 acc;
    #pragma unroll
    for (int r = 0; r < 16; r++) acc[r] = 0.f;

    stage(0, 0); stage(1, 64);
    int cur = 0, arow = wr * 32 + col, brow = wc * 32 + col;
    #pragma unroll 1
    for (int kt = 0; kt < 17; kt++) {
        asm volatile("s_waitcnt vmcnt(4)" ::: "memory");
        __builtin_amdgcn_s_barrier();
        __builtin_amdgcn_sched_barrier(0);
        __builtin_amdgcn_s_setprio(1);
        #pragma unroll
        for (int kk = 0; kk < 4; kk++) {
            int ch = kk * 2 + half;
            f16x8 af = *(const f16x8*)&As[cur][arow * 64 + ((ch ^ (arow & 7)) << 3)];
            f16x8 bf = *(const f16x8*)&Bs[cur][brow * 64 + ((ch ^ (brow & 7)) << 3)];
            acc = __builtin_amdgcn_mfma_f32_32x32x16_f16(af, bf, acc, 0, 0, 0);
        }
        __builtin_amdgcn_s_setprio(0);
        __builtin_amdgcn_sched_barrier(0);
        __builtin_amdgcn_s_barrier();
        if (kt < 16) stage(cur, (kt + 2) * 64);
        cur ^= 1;
    }
    asm volatile("s_waitcnt vmcnt(0)" ::: "memory");
    __builtin_amdgcn_s_barrier();
    __builtin_amdgcn_sched_barrier(0);
    #pragma unroll
    for (int kk = 0; kk < 4; kk++) {
        int ch = kk * 2 + half;
        f16x8 af = *(const f16x8*)&As[cur][arow * 64 + ((ch ^ (arow & 7)) << 3)];
        f16x8 bf = *(const f16x8*)&Bs[cur][brow * 64 + ((ch ^ (brow & 7)) << 3)];
        acc = __builtin_amdgcn_mfma_f32_32x32x16_f16(af, bf, acc, 0, 0, 0);
    }

    #pragma unroll
    for (int r = 0; r < 16; r++) {
        int m = m0 + wr * 32 + (r & 3) + 8 * (r >> 2) + 4 * half;
        int n = n0 + wc * 32 + col;
        float v = fmaxf(acc[r] + bias[n], 0.f);
        h16[(size_t)m * EMB + n] = (f16)v;
    }
}

// ---------- fused GRU step: 128x64 tile, 8 waves, counted-vmcnt pipeline ----------
__global__ __launch_bounds__(512) void gru_step(
    const f16* __restrict__ h16_in, f16* __restrict__ h16_out,
    const f16* __restrict__ w16,          // [1536][512]
    const float* __restrict__ b_hh,
    const float* __restrict__ w_ih, const float* __restrict__ b_ih,
    const float* __restrict__ dec_w,
    float* __restrict__ out, int t)
{
    __shared__ __align__(16) f16 As[2][128 * 64];   // 2 x 16 KB
    __shared__ __align__(16) f16 Bs[2][192 * 64];   // 2 x 24 KB
    int tid = threadIdx.x, wid = tid >> 6, lane = tid & 63;
    int wsub = wid >> 1, wc = wid & 1;
    int col = lane & 31, half = lane >> 5;

    // XCD remap: XCD (= bx under %8 round-robin) owns m-groups [4bx,4bx+4) x all e
    int m0 = (blockIdx.x * 4 + (blockIdx.y >> 3)) * 128;
    int e0 = (blockIdx.y & 7) * 64;
    int e = e0 + wc * 32 + col;

    // hoist ALL epilogue operands: latency hides under the GEMM
    float wir = w_ih[e], wiz = w_ih[EMB + e], win = w_ih[2 * EMB + e];
    float bir = b_ih[e], biz = b_ih[EMB + e], bin_ = b_ih[2 * EMB + e];
    float bhr = b_hh[e], bhz = b_hh[EMB + e], bhn = b_hh[2 * EMB + e];
    float dw  = dec_w[e];
    int   mrow[16]; float prevv[16], hpv[16];
    int tprev = (t > 0) ? t - 1 : 0;
    #pragma unroll
    for (int r = 0; r < 16; r++) {
        int m = m0 + wsub * 32 + (r & 3) + 8 * (r >> 2) + 4 * half;
        mrow[r] = m;
        float pv = out[(size_t)m * TSTEP + tprev];      // always in-bounds
        prevv[r] = (t > 0) ? pv : 0.f;
        hpv[r]   = (float)h16_in[(size_t)m * EMB + e];
    }

    const f16* gA[2]; const f16* gB[3];
    #pragma unroll
    for (int a = 0; a < 2; a++) {
        int q = a * 512 + tid, row = q >> 3, cp = q & 7, c = cp ^ (row & 7);
        gA[a] = h16_in + (size_t)(m0 + row) * EMB + c * 8;
    }
    #pragma unroll
    for (int bq = 0; bq < 3; bq++) {
        int q = bq * 512 + tid, row = q >> 3, cp = q & 7, c = cp ^ (row & 7);
        int R = (row >> 6) * EMB + e0 + (row & 63);     // gate*512 + e
        gB[bq] = w16 + (size_t)R * EMB + c * 8;
    }
    auto stage = [&](int buf, int k0) {
        #pragma unroll
        for (int a = 0; a < 2; a++)
            __builtin_amdgcn_global_load_lds((const g_void_t*)(gA[a] + k0),
                (lds_void_t*)((char*)&As[buf][0] + (a * 512 + wid * 64) * 16), 16, 0, 0);
        #pragma unroll
        for (int bq = 0; bq < 3; bq++)
            __builtin_amdgcn_global_load_lds((const g_void_t*)(gB[bq] + k0),
                (lds_void_t*)((char*)&Bs[buf][0] + (bq * 512 + wid * 64) * 16), 16, 0, 0);
    };

    f32x16 acc[3];
    #pragma unroll
    for (int g = 0; g < 3; g++)
        #pragma unroll
        for (int r = 0; r < 16; r++) acc[g][r] = 0.f;

    stage(0, 0); stage(1, 64);
    int cur = 0, arow = wsub * 32 + col;
    #pragma unroll 1
    for (int kt = 0; kt < 7; kt++) {
        asm volatile("s_waitcnt vmcnt(5)" ::: "memory");
        __builtin_amdgcn_s_barrier();
        __builtin_amdgcn_sched_barrier(0);
        __builtin_amdgcn_s_setprio(1);
        #pragma unroll
        for (int kk = 0; kk < 4; kk++) {
            int ch = kk * 2 + half;
            f16x8 af = *(const f16x8*)&As[cur][arow * 64 + ((ch ^ (arow & 7)) << 3)];
            #pragma unroll
            for (int g = 0; g < 3; g++) {
                int br = g * 64 + wc * 32 + col;
                f16x8 bf = *(const f16x8*)&Bs[cur][br * 64 + ((ch ^ (br & 7)) << 3)];
                acc[g] = __builtin_amdgcn_mfma_f32_32x32x16_f16(af, bf, acc[g], 0, 0, 0);
            }
        }
        __builtin_amdgcn_s_setprio(0);
        __builtin_amdgcn_sched_barrier(0);
        __builtin_amdgcn_s_barrier();
        if (kt < 6) stage(cur, (kt + 2) * 64);
        cur ^= 1;
    }
    asm volatile("s_waitcnt vmcnt(0)" ::: "memory");
    __builtin_amdgcn_s_barrier();
    __builtin_amdgcn_sched_barrier(0);
    #pragma unroll
    for (int kk = 0; kk < 4; kk++) {
        int ch = kk * 2 + half;
        f16x8 af = *(const f16x8*)&As[cur][arow * 64 + ((ch ^ (arow & 7)) << 3)];
        #pragma unroll
        for (int g = 0; g < 3; g++) {
            int br = g * 64 + wc * 32 + col;
            f16x8 bf = *(const f16x8*)&Bs[cur][br * 64 + ((ch ^ (br & 7)) << 3)];
            acc[g] = __builtin_amdgcn_mfma_f32_32x32x16_f16(af, bf, acc[g], 0, 0, 0);
        }
    }

    #pragma unroll
    for (int r = 0; r < 16; r++) {
        int m = mrow[r];
        float prev = prevv[r];
        float gr  = acc[0][r] + bhr + fmaf(prev, wir, bir);
        float gz  = acc[1][r] + bhz + fmaf(prev, wiz, biz);
        float ghn = acc[2][r] + bhn;
        float gin = fmaf(prev, win, bin_);
        float rr = sigmoid_fast(gr);
        float zz = sigmoid_fast(gz);
        float nn = tanh_fast(fmaf(rr, ghn, gin));
        float hn = fmaf(zz, hpv[r] - nn, nn);           // (1-z)n + z*hp
        h16_out[(size_t)m * EMB + e] = (f16)hn;
        float v = hn * dw;
        v += __shfl_xor(v, 1);  v += __shfl_xor(v, 2);
        v += __shfl_xor(v, 4);  v += __shfl_xor(v, 8);
        v += __shfl_xor(v, 16);
        if (col == 0) atomicAdd(&out[(size_t)m * TSTEP + t], v);
    }
}

extern "C" void kernel_launch(void* const* d_in, const int* in_sizes, int n_in,
                              void* d_out, int out_size, void* d_ws, size_t ws_size,
                              hipStream_t stream)
{
    const float* x      = (const float*)d_in[0];
    const float* conv_w = (const float*)d_in[1];
    const float* conv_b = (const float*)d_in[2];
    const float* fc_w   = (const float*)d_in[3];
    const float* fc_b   = (const float*)d_in[4];
    const float* w_ih   = (const float*)d_in[5];
    const float* b_ih   = (const float*)d_in[6];
    const float* w_hh   = (const float*)d_in[7];
    const float* b_hh   = (const float*)d_in[8];
    const float* dec_w  = (const float*)d_in[9];
    const float* dec_b  = (const float*)d_in[10];
    float* out = (float*)d_out;

    char* ws = (char*)d_ws;
    // layout (bytes):
    //   [0,         9437184)   convbuf16 [4096][1152] f16 (pos*32+co order)
    //   [9437184,  13631488)   h16_a [4096][512]
    //   [13631488, 17825792)   h16_b [4096][512]
    //   [17825792, 19398656)   w16   [1536][512]
    //   [19398656, 19435520)   w16c  [9][32][64] swizzled
    //   [19435520, 20615168)   fcp16 [512][1152] permuted
    f16*   convbuf16 = (f16*)ws;
    f16*   h16_a     = (f16*)(ws + 9437184);
    f16*   h16_b     = (f16*)(ws + 13631488);
    f16*   w16       = (f16*)(ws + 17825792);
    f16*   w16c      = (f16*)(ws + 19398656);
    f16*   fcp16     = (f16*)(ws + 19435520);

    int prep_n = G3 * EMB + 9 * 32 * 64 + EMB * KFC + B_ * TSTEP;
    prep_kernel<<<(prep_n + 255) / 256, 256, 0, stream>>>(
        w_hh, w16, conv_w, w16c, fc_w, fcp16, dec_b, out);

    conv_mfma<<<B_ / 8, 256, 0, stream>>>(x, w16c, conv_b, convbuf16);
    fc_mfma<<<dim3(EMB / 64, B_ / 64), 256, 0, stream>>>(convbuf16, fcp16, fc_b, h16_a);

    for (int t = 0; t < TSTEP; t++) {
        const f16* hi = (t & 1) ? h16_b : h16_a;
        f16*       ho = (t & 1) ? h16_a : h16_b;
        gru_step<<<dim3(8, 32), 512, 0, stream>>>(
            hi, ho, w16, b_hh, w_ih, b_ih, dec_w, out, t);
    }
}